// Round 8
// baseline (2404.668 us; speedup 1.0000x reference)
//
#include <hip/hip_runtime.h>

#define N_NODES 50000
#define N_EDGES 200000
#define D 200
#define NLAYERS 10
#define NGRAPH 2500
#define EPS 1e-5f

typedef unsigned short u16;
typedef unsigned int u32;
typedef __attribute__((ext_vector_type(8))) __bf16 bf16x8;
typedef __attribute__((ext_vector_type(4))) float f32x4;

typedef __attribute__((address_space(3))) u32 as3_u32;
typedef __attribute__((address_space(1))) const u32 as1_u32;

// async global->LDS, 16B per lane; LDS dest = wave-uniform base + lane*16
__device__ __forceinline__ void gload16(const u32* g, u32* l) {
    __builtin_amdgcn_global_load_lds((as1_u32*)g, (as3_u32*)l, 16, 0, 0);
}

// fp32 -> bf16 RNE
__device__ __forceinline__ u16 f2bf_rne(float x) {
    union { float f; unsigned u; } c; c.f = x;
    unsigned r = c.u + 0x7FFF + ((c.u >> 16) & 1);
    return (u16)(r >> 16);
}
// packed: low u16 = hi bf16, high u16 = lo bf16
__device__ __forceinline__ u32 split_pack(float x) {
    u16 h = f2bf_rne(x);
    union { unsigned u; float f; } c; c.u = ((unsigned)h) << 16;
    u16 l = f2bf_rne(x - c.f);
    return (u32)h | ((u32)l << 16);
}

// unpack 8 packed u32 (2x uint4, elems k0..k3 / k4..k7) -> hi frag + lo frag
__device__ __forceinline__ void unpack_pair(uint4 q1, uint4 q2, bf16x8& hi, bf16x8& lo) {
    uint4 h, l;
    h.x = __byte_perm(q1.x, q1.y, 0x5410); h.y = __byte_perm(q1.z, q1.w, 0x5410);
    h.z = __byte_perm(q2.x, q2.y, 0x5410); h.w = __byte_perm(q2.z, q2.w, 0x5410);
    l.x = __byte_perm(q1.x, q1.y, 0x7632); l.y = __byte_perm(q1.z, q1.w, 0x7632);
    l.z = __byte_perm(q2.x, q2.y, 0x7632); l.w = __byte_perm(q2.z, q2.w, 0x7632);
    hi = *(bf16x8*)&h; lo = *(bf16x8*)&l;
}

// ---------------- CSR build -------------------------------------------------

__global__ void count_kernel(const int* __restrict__ dst, int* __restrict__ counts) {
    int e = blockIdx.x * 256 + threadIdx.x;
    if (e < N_EDGES) atomicAdd(&counts[dst[e]], 1);
}

__global__ void scan1_kernel(const int* __restrict__ counts, int* __restrict__ psum) {
    __shared__ int s[256];
    int idx = blockIdx.x * 256 + threadIdx.x;
    s[threadIdx.x] = (idx < N_NODES) ? counts[idx] : 0;
    __syncthreads();
    for (int off = 128; off > 0; off >>= 1) {
        if (threadIdx.x < off) s[threadIdx.x] += s[threadIdx.x + off];
        __syncthreads();
    }
    if (threadIdx.x == 0) psum[blockIdx.x] = s[0];
}

__global__ void scan2_kernel(const int* __restrict__ psum, int* __restrict__ poff, int nchunk) {
    __shared__ int s[256];
    int t = threadIdx.x;
    int v = (t < nchunk) ? psum[t] : 0;
    s[t] = v;
    __syncthreads();
    for (int off = 1; off < 256; off <<= 1) {
        int xv = (t >= off) ? s[t - off] : 0;
        __syncthreads();
        s[t] += xv;
        __syncthreads();
    }
    if (t < nchunk) poff[t] = s[t] - v;
}

__global__ void scan3_kernel(const int* __restrict__ counts, const int* __restrict__ poff,
                             int* __restrict__ row_start, int* __restrict__ cursor) {
    __shared__ int s[256];
    int t = threadIdx.x;
    int idx = blockIdx.x * 256 + t;
    int v = (idx < N_NODES) ? counts[idx] : 0;
    s[t] = v;
    __syncthreads();
    for (int off = 1; off < 256; off <<= 1) {
        int xv = (t >= off) ? s[t - off] : 0;
        __syncthreads();
        s[t] += xv;
        __syncthreads();
    }
    if (idx < N_NODES) {
        int rs = poff[blockIdx.x] + s[t] - v;
        row_start[idx] = rs;
        cursor[idx] = rs;
    }
    if (blockIdx.x == 0 && t == 0) row_start[N_NODES] = N_EDGES;
}

__global__ void scatter_kernel(const int* __restrict__ dst, int* __restrict__ cursor,
                               int* __restrict__ edge_list) {
    int e = blockIdx.x * 256 + threadIdx.x;
    if (e < N_EDGES) {
        int p = atomicAdd(&cursor[dst[e]], 1);
        edge_list[p] = e;
    }
}

__global__ void bounds_kernel(const int* __restrict__ batch, int* __restrict__ gstart) {
    int g = blockIdx.x * 256 + threadIdx.x;
    if (g > NGRAPH) return;
    if (g == NGRAPH) { gstart[NGRAPH] = N_NODES; return; }
    int lo = 0, hi = N_NODES;
    while (lo < hi) { int mid = (lo + hi) >> 1; if (batch[mid] < g) lo = mid + 1; else hi = mid; }
    gstart[g] = lo;
}

// ---------------- weight prep: transpose + pad + packed hi/lo bf16 -----------

__global__ void prep_w1_kernel(const float* __restrict__ w, u32* __restrict__ wp) {
    int idx = blockIdx.x * 256 + threadIdx.x;
    if (idx >= NLAYERS * 512 * 224) return;
    int k = idx % 224;
    int n = (idx / 224) % 512;
    int l = idx / (224 * 512);
    float v = (k < 200 && n < 400) ? w[((size_t)l * 200 + k) * 400 + n] : 0.f;
    wp[idx] = split_pack(v);
}

__global__ void prep_w2_kernel(const float* __restrict__ w, u32* __restrict__ wp) {
    int idx = blockIdx.x * 256 + threadIdx.x;
    if (idx >= NLAYERS * 256 * 416) return;
    int k = idx % 416;
    int n = (idx / 416) % 256;
    int l = idx / (416 * 256);
    float v = (k < 400 && n < 200) ? w[((size_t)l * 400 + k) * 200 + n] : 0.f;
    wp[idx] = split_pack(v);
}

// ---------------- node feature init ------------------------------------------

__global__ void embed_kernel(const int* __restrict__ x, const float* __restrict__ emb1,
                             const float* __restrict__ emb2, float* __restrict__ h) {
    int idx = blockIdx.x * 256 + threadIdx.x;
    if (idx >= N_NODES * 50) return;
    int node = idx / 50;
    int c = (idx % 50) * 4;
    int a = x[node * 2], b = x[node * 2 + 1];
    float4 v1 = *(const float4*)(emb1 + (size_t)a * D + c);
    float4 v2 = *(const float4*)(emb2 + (size_t)b * D + c);
    float4 o;
    o.x = v1.x + v2.x; o.y = v1.y + v2.y; o.z = v1.z + v2.z; o.w = v1.w + v2.w;
    *(float4*)(h + (size_t)node * D + c) = o;
}

// ---------------- message + aggregate (+fused BN-norm+ReLU of prev layer) ----

template <int HAS_BN>
__global__ void aggregate_kernel(const float* __restrict__ hin,
                                 const float* __restrict__ stats,
                                 const float* __restrict__ gamma, const float* __restrict__ beta,
                                 const float* __restrict__ e1, const float* __restrict__ e2,
                                 const int* __restrict__ row_start, const int* __restrict__ edge_list,
                                 const int* __restrict__ src, const int* __restrict__ edge_attr,
                                 u32* __restrict__ Ap) {
    __shared__ float t1[5 * D];
    __shared__ float t2[3 * D];
    for (int i = threadIdx.x; i < 5 * D; i += 256) t1[i] = e1[i];
    for (int i = threadIdx.x; i < 3 * D; i += 256) t2[i] = e2[i];
    __syncthreads();
    int idx = blockIdx.x * 256 + threadIdx.x;
    if (idx >= N_NODES * 56) return;
    int node = idx / 56;
    int c = (idx % 56) * 4;
    size_t ob = (size_t)node * 224 + c;
    if (c >= 200) {  // K padding cols 200..223
        *(uint4*)(Ap + ob) = make_uint4(0u, 0u, 0u, 0u);
        return;
    }
    float a[4], b[4];
    if (HAS_BN) {
        const float invN = 1.0f / (float)N_NODES;
#pragma unroll
        for (int j = 0; j < 4; ++j) {
            float s = stats[c + j], q = stats[256 + c + j];
            float m = s * invN;
            float var = q * invN - m * m;
            float sc = gamma[c + j] * rsqrtf(var + EPS);
            a[j] = sc; b[j] = beta[c + j] - m * sc;
        }
    }
    float4 acc = *(const float4*)(hin + (size_t)node * D + c);
    if (HAS_BN) {
        acc.x = fmaxf(acc.x * a[0] + b[0], 0.f);
        acc.y = fmaxf(acc.y * a[1] + b[1], 0.f);
        acc.z = fmaxf(acc.z * a[2] + b[2], 0.f);
        acc.w = fmaxf(acc.w * a[3] + b[3], 0.f);
    }
    acc.x += t1[4 * D + c + 0] + t2[c + 0];
    acc.y += t1[4 * D + c + 1] + t2[c + 1];
    acc.z += t1[4 * D + c + 2] + t2[c + 2];
    acc.w += t1[4 * D + c + 3] + t2[c + 3];
    int jb = row_start[node], je = row_start[node + 1];
    for (int j = jb; j < je; ++j) {
        int e = edge_list[j];
        int s = src[e];
        int2 eav = *(const int2*)(edge_attr + 2 * e);
        float4 hv = *(const float4*)(hin + (size_t)s * D + c);
        if (HAS_BN) {
            hv.x = fmaxf(hv.x * a[0] + b[0], 0.f);
            hv.y = fmaxf(hv.y * a[1] + b[1], 0.f);
            hv.z = fmaxf(hv.z * a[2] + b[2], 0.f);
            hv.w = fmaxf(hv.w * a[3] + b[3], 0.f);
        }
        const float* p1 = t1 + eav.x * D + c;
        const float* p2 = t2 + eav.y * D + c;
        acc.x += hv.x + p1[0] + p2[0];
        acc.y += hv.y + p1[1] + p2[1];
        acc.z += hv.z + p1[2] + p2[2];
        acc.w += hv.w + p1[3] + p2[3];
    }
    uint4 pv;
    pv.x = split_pack(acc.x); pv.y = split_pack(acc.y);
    pv.z = split_pack(acc.z); pv.w = split_pack(acc.w);
    *(uint4*)(Ap + ob) = pv;
}

// ---------------- bf16x2 MFMA GEMM, global_load_lds staging (m97 structure) --
// Block tile (FM*32) x (FN*32), 4 waves 2x2, K-step 32 (packed u32 rows of 32).
// LDS: packed u32 [rows][32], LINEAR dest (gload_lds writes base+lane*16).
// Swizzle lives in the per-lane GLOBAL source: LDS[r][unit j] holds global
// unit (j ^ (r&7)); fragment reads apply the same XOR -> every 8-lane phase
// group covers all 8 units once (conflict-free). Unpack hi/lo at read time.
// XCD-bijective block swizzle (m204) for A row-band L2 locality.

template <int FM, int FN, int GXL, int RELU, int WRITE_PACKED, int STATS>
__global__ __launch_bounds__(256) void gemm_mfma(
    const u32* __restrict__ Ap, const u32* __restrict__ Bp,
    const float* __restrict__ bias,
    float* __restrict__ Cf, u32* __restrict__ Cp,
    float* __restrict__ stats,
    int M, int Kpad, int Nc, int NcPad, int KT)
{
    constexpr int BMT = FM * 32;           // block M tile (64 or 128)
    constexpr int BNTL = FN * 32;          // block N tile (128)
    constexpr int NIA = BMT / 32;          // gload instr per wave for A (2 or 4)
    constexpr int NIB = BNTL / 32;         // 4

    __shared__ alignas(16) u32 sA[BMT * 32];
    __shared__ alignas(16) u32 sB[BNTL * 32];

    const int tid = threadIdx.x;
    const int lane = tid & 63;
    const int w = tid >> 6;
    const int wm = w >> 1, wn = w & 1;
    const int lr = lane & 15, lg = lane >> 4;

    // XCD-bijective block swizzle: consecutive wgid -> same XCD
    const int nwg = (int)(gridDim.x * gridDim.y);
    const int id = (int)(blockIdx.y * gridDim.x + blockIdx.x);
    const int q = nwg >> 3, rm = nwg & 7;
    const int xcd = id & 7, sub = id >> 3;
    const int wgid = (xcd < rm ? xcd * (q + 1) : rm * (q + 1) + (xcd - rm) * q) + sub;
    const int bm0 = (wgid >> GXL) * BMT;
    const int bn0 = (wgid & ((1 << GXL) - 1)) * BNTL;

    // staging source pointers: instr i covers LDS chunk c (8 rows x 8 units);
    // lane l -> row c*8+(l>>3), LDS unit l&7, global unit (l&7)^(row&7)
    const u32* ga[NIA]; const u32* gb[NIB];
    u32* la[NIA]; u32* lb[NIB];
#pragma unroll
    for (int i = 0; i < NIA; ++i) {
        int c = w * NIA + i;
        int r = c * 8 + (lane >> 3);
        int j = (lane & 7) ^ (r & 7);
        ga[i] = Ap + (size_t)(bm0 + r) * Kpad + j * 4;
        la[i] = sA + c * 256;              // wave-uniform
    }
#pragma unroll
    for (int i = 0; i < NIB; ++i) {
        int c = w * NIB + i;
        int r = c * 8 + (lane >> 3);
        int j = (lane & 7) ^ (r & 7);
        gb[i] = Bp + (size_t)(bn0 + r) * Kpad + j * 4;
        lb[i] = sB + c * 256;
    }

    f32x4 acc[FM][FN];
#pragma unroll
    for (int i = 0; i < FM; ++i)
#pragma unroll
        for (int j = 0; j < FN; ++j) acc[i][j] = (f32x4){0.f, 0.f, 0.f, 0.f};

    // fragment read offsets (u32 units): row&7 == lr&7 (tile bases mult of 16)
    const int sx = lr & 7;
    const int u1 = ((2 * lg) ^ sx) * 4;
    const int u2 = ((2 * lg + 1) ^ sx) * 4;
    int aoff[FM], boff[FN];
#pragma unroll
    for (int f = 0; f < FM; ++f) aoff[f] = (wm * FM * 16 + f * 16 + lr) * 32;
#pragma unroll
    for (int f = 0; f < FN; ++f) boff[f] = (wn * FN * 16 + f * 16 + lr) * 32;

    for (int kt = 0; kt < KT; ++kt) {
        const int ko = kt * 32;
#pragma unroll
        for (int i = 0; i < NIA; ++i) gload16(ga[i] + ko, la[i]);
#pragma unroll
        for (int i = 0; i < NIB; ++i) gload16(gb[i] + ko, lb[i]);
        __syncthreads();   // drains vmcnt -> LDS tile ready

        bf16x8 fbh[FN], fbl[FN];
#pragma unroll
        for (int fn = 0; fn < FN; ++fn) {
            uint4 q1 = *(const uint4*)(sB + boff[fn] + u1);
            uint4 q2 = *(const uint4*)(sB + boff[fn] + u2);
            unpack_pair(q1, q2, fbh[fn], fbl[fn]);
        }
#pragma unroll
        for (int fm = 0; fm < FM; ++fm) {
            uint4 q1 = *(const uint4*)(sA + aoff[fm] + u1);
            uint4 q2 = *(const uint4*)(sA + aoff[fm] + u2);
            bf16x8 fah, fal;
            unpack_pair(q1, q2, fah, fal);
#pragma unroll
            for (int fn = 0; fn < FN; ++fn) {
                acc[fm][fn] = __builtin_amdgcn_mfma_f32_16x16x32_bf16(fah, fbh[fn], acc[fm][fn], 0, 0, 0);
                acc[fm][fn] = __builtin_amdgcn_mfma_f32_16x16x32_bf16(fah, fbl[fn], acc[fm][fn], 0, 0, 0);
                acc[fm][fn] = __builtin_amdgcn_mfma_f32_16x16x32_bf16(fal, fbh[fn], acc[fm][fn], 0, 0, 0);
            }
        }
        __syncthreads();   // all reads done before next tile overwrites
    }

    // epilogue: frag D row = lg*4+r, col = lr
#pragma unroll
    for (int fn = 0; fn < FN; ++fn) {
        int col = bn0 + wn * FN * 16 + fn * 16 + lr;
        float bv = (col < Nc) ? bias[col] : 0.f;
        if (WRITE_PACKED) {
            if (col < NcPad) {
#pragma unroll
                for (int fm = 0; fm < FM; ++fm) {
#pragma unroll
                    for (int r = 0; r < 4; ++r) {
                        int row = bm0 + wm * FM * 16 + fm * 16 + lg * 4 + r;
                        if (row < M) {
                            float v = acc[fm][fn][r] + bv;
                            if (RELU) v = fmaxf(v, 0.f);
                            if (col >= Nc) v = 0.f;   // h1 K-padding cols must be 0
                            Cp[(size_t)row * NcPad + col] = split_pack(v);
                        }
                    }
                }
            }
        } else {
            float s = 0.f, q2 = 0.f;
#pragma unroll
            for (int fm = 0; fm < FM; ++fm) {
#pragma unroll
                for (int r = 0; r < 4; ++r) {
                    int row = bm0 + wm * FM * 16 + fm * 16 + lg * 4 + r;
                    if (row < M && col < Nc) {
                        float v = acc[fm][fn][r] + bv;
                        if (RELU) v = fmaxf(v, 0.f);
                        Cf[(size_t)row * Nc + col] = v;
                        if (STATS) { s += v; q2 += v * v; }
                    }
                }
            }
            if (STATS) {
                s += __shfl_xor(s, 16); s += __shfl_xor(s, 32);
                q2 += __shfl_xor(q2, 16); q2 += __shfl_xor(q2, 32);
                if (lg == 0 && col < Nc) {
                    atomicAdd(&stats[col], s);
                    atomicAdd(&stats[256 + col], q2);
                }
            }
        }
    }
}

// ---------------- fp32 tiled GEMM (tail, small M) ----------------------------

#define BM 128
#define BNT 64
#define BK 8

__global__ __launch_bounds__(256) void gemm_kernel(const float* __restrict__ A,
                                                   const float* __restrict__ W,
                                                   const float* __restrict__ bias,
                                                   float* __restrict__ C,
                                                   int M, int K, int Nc, int relu) {
    __shared__ float As[BK][BM];
    __shared__ float Bs[BK][BNT];
    int tid = threadIdx.x;
    int bm = blockIdx.x * BM;
    int bn = blockIdx.y * BNT;
    int tx = tid & 15, ty = tid >> 4;

    float acc[8][4];
#pragma unroll
    for (int i = 0; i < 8; ++i)
#pragma unroll
        for (int j = 0; j < 4; ++j) acc[i][j] = 0.f;

    int ar = tid >> 1;
    int ak = (tid & 1) << 2;
    int bk = tid >> 5;
    int bcol = (tid & 31) << 1;

    for (int k0 = 0; k0 < K; k0 += BK) {
        float4 av = {0.f, 0.f, 0.f, 0.f};
        int row = bm + ar;
        if (row < M) av = *(const float4*)(A + (size_t)row * K + k0 + ak);
        As[ak + 0][ar] = av.x; As[ak + 1][ar] = av.y;
        As[ak + 2][ar] = av.z; As[ak + 3][ar] = av.w;
        float2 bv = {0.f, 0.f};
        int col = bn + bcol;
        if (col < Nc) bv = *(const float2*)(W + (size_t)(k0 + bk) * Nc + col);
        Bs[bk][bcol] = bv.x; Bs[bk][bcol + 1] = bv.y;
        __syncthreads();
#pragma unroll
        for (int kk = 0; kk < BK; ++kk) {
            float a[8], b[4];
            *(float4*)(a)     = *(const float4*)(&As[kk][ty * 8]);
            *(float4*)(a + 4) = *(const float4*)(&As[kk][ty * 8 + 4]);
            *(float4*)(b)     = *(const float4*)(&Bs[kk][tx * 4]);
#pragma unroll
            for (int i = 0; i < 8; ++i)
#pragma unroll
                for (int j = 0; j < 4; ++j) acc[i][j] = fmaf(a[i], b[j], acc[i][j]);
        }
        __syncthreads();
    }

#pragma unroll
    for (int i = 0; i < 8; ++i) {
        int row = bm + ty * 8 + i;
        if (row < M) {
            int col = bn + tx * 4;
            if (col < Nc) {
                float4 bb = *(const float4*)(bias + col);
                float4 v;
                v.x = acc[i][0] + bb.x; v.y = acc[i][1] + bb.y;
                v.z = acc[i][2] + bb.z; v.w = acc[i][3] + bb.w;
                if (relu) {
                    v.x = fmaxf(v.x, 0.f); v.y = fmaxf(v.y, 0.f);
                    v.z = fmaxf(v.z, 0.f); v.w = fmaxf(v.w, 0.f);
                }
                *(float4*)(C + (size_t)row * Nc + col) = v;
            }
        }
    }
}

// ---------------- global mean pool (+fused BN of last layer, no relu) --------

__global__ void pool_bn_kernel(const float* __restrict__ g2, const float* __restrict__ stats,
                               const float* __restrict__ gamma, const float* __restrict__ beta,
                               const int* __restrict__ gstart, float* __restrict__ hg) {
    int idx = blockIdx.x * 256 + threadIdx.x;
    if (idx >= NGRAPH * 50) return;
    int g = idx / 50;
    int c = (idx % 50) * 4;
    float a[4], b[4];
    const float invN = 1.0f / (float)N_NODES;
#pragma unroll
    for (int j = 0; j < 4; ++j) {
        float s = stats[c + j], q = stats[256 + c + j];
        float m = s * invN;
        float var = q * invN - m * m;
        float sc = gamma[c + j] * rsqrtf(var + EPS);
        a[j] = sc; b[j] = beta[c + j] - m * sc;
    }
    int s0 = gstart[g], e0 = gstart[g + 1];
    float4 acc = {0.f, 0.f, 0.f, 0.f};
    for (int r = s0; r < e0; ++r) {
        float4 v = *(const float4*)(g2 + (size_t)r * D + c);
        acc.x += v.x; acc.y += v.y; acc.z += v.z; acc.w += v.w;
    }
    float inv = 1.0f / fmaxf((float)(e0 - s0), 1.0f);
    acc.x = acc.x * inv * a[0] + b[0];
    acc.y = acc.y * inv * a[1] + b[1];
    acc.z = acc.z * inv * a[2] + b[2];
    acc.w = acc.w * inv * a[3] + b[3];
    *(float4*)(hg + (size_t)g * D + c) = acc;
}

// ---------------- launch -------------------------------------------------------

extern "C" void kernel_launch(void* const* d_in, const int* in_sizes, int n_in,
                              void* d_out, int out_size, void* d_ws, size_t ws_size,
                              hipStream_t stream) {
    const int*   x       = (const int*)d_in[0];
    const int*   ei      = (const int*)d_in[1];
    const int*   ea      = (const int*)d_in[2];
    const int*   batch   = (const int*)d_in[3];
    const float* x_emb1  = (const float*)d_in[4];
    const float* x_emb2  = (const float*)d_in[5];
    const float* e1w     = (const float*)d_in[6];
    const float* e2w     = (const float*)d_in[7];
    const float* w1      = (const float*)d_in[8];
    const float* b1      = (const float*)d_in[9];
    const float* w2      = (const float*)d_in[10];
    const float* b2      = (const float*)d_in[11];
    const float* gamma   = (const float*)d_in[12];
    const float* beta    = (const float*)d_in[13];
    const float* feat_w  = (const float*)d_in[14];
    const float* feat_b  = (const float*)d_in[15];
    const float* out_w1  = (const float*)d_in[16];
    const float* out_b1  = (const float*)d_in[17];
    const float* out_w2  = (const float*)d_in[18];
    const float* out_b2  = (const float*)d_in[19];
    const int* src = ei;
    const int* dst = ei + N_EDGES;

    char* p = (char*)d_ws;
    auto alloc = [&](size_t bytes) -> void* {
        void* r = (void*)p;
        p += (bytes + 255) & ~(size_t)255;
        return r;
    };
    const int MPAD = 50048;                         // 391*128 == 782*64
    float* h      = (float*)alloc((size_t)N_NODES * D * 4);          // 40 MB
    float* g2     = h;
    u32*   aggrP  = (u32*)alloc((size_t)MPAD * 224 * 4);             // 44.8 MB
    u32*   h1p    = (u32*)alloc((size_t)MPAD * 416 * 4);             // 83.3 MB
    u32*   wt1p   = (u32*)alloc((size_t)NLAYERS * 512 * 224 * 4);    // 4.6 MB
    u32*   wt2p   = (u32*)alloc((size_t)NLAYERS * 256 * 416 * 4);    // 4.3 MB
    int*   counts    = (int*)alloc(N_NODES * 4);
    int*   row_start = (int*)alloc((N_NODES + 1) * 4);
    int*   cursor    = (int*)alloc(N_NODES * 4);
    int*   edge_list = (int*)alloc(N_EDGES * 4);
    int*   psum      = (int*)alloc(256 * 4);
    int*   poff      = (int*)alloc(256 * 4);
    int*   gstart    = (int*)alloc((NGRAPH + 1) * 4);
    float* stats     = (float*)alloc(512 * 4);       // [sum 256][sumsq 256]
    float* hg        = (float*)alloc((size_t)NGRAPH * D * 4);
    float* tbuf      = (float*)alloc((size_t)NGRAPH * D * 4);
    float* outf      = (float*)d_out;

    const int NCHUNK = (N_NODES + 255) / 256;

    // weight prep (once per launch)
    prep_w1_kernel<<<(NLAYERS * 512 * 224 + 255) / 256, 256, 0, stream>>>(w1, wt1p);
    prep_w2_kernel<<<(NLAYERS * 256 * 416 + 255) / 256, 256, 0, stream>>>(w2, wt2p);

    // CSR build + graph bounds
    hipMemsetAsync(counts, 0, N_NODES * 4, stream);
    count_kernel<<<(N_EDGES + 255) / 256, 256, 0, stream>>>(dst, counts);
    scan1_kernel<<<NCHUNK, 256, 0, stream>>>(counts, psum);
    scan2_kernel<<<1, 256, 0, stream>>>(psum, poff, NCHUNK);
    scan3_kernel<<<NCHUNK, 256, 0, stream>>>(counts, poff, row_start, cursor);
    scatter_kernel<<<(N_EDGES + 255) / 256, 256, 0, stream>>>(dst, cursor, edge_list);
    bounds_kernel<<<(NGRAPH + 1 + 255) / 256, 256, 0, stream>>>(batch, gstart);

    embed_kernel<<<(N_NODES * 50 + 255) / 256, 256, 0, stream>>>(x, x_emb1, x_emb2, h);

    dim3 g1(4, 391);    // GEMM1: 128x128 tiles, N pad 512  (GXL=2)
    dim3 g2d(2, 782);   // GEMM2: 64x128 tiles, N pad 256   (GXL=1)
    for (int l = 0; l < NLAYERS; ++l) {
        if (l == 0)
            aggregate_kernel<0><<<(N_NODES * 56 + 255) / 256, 256, 0, stream>>>(
                h, nullptr, nullptr, nullptr,
                e1w, e2w, row_start, edge_list, src, ea, aggrP);
        else
            aggregate_kernel<1><<<(N_NODES * 56 + 255) / 256, 256, 0, stream>>>(
                g2, stats, gamma + (size_t)(l - 1) * D, beta + (size_t)(l - 1) * D,
                e1w + (size_t)l * 5 * D, e2w + (size_t)l * 3 * D,
                row_start, edge_list, src, ea, aggrP);
        gemm_mfma<4, 4, 2, 1, 1, 0><<<g1, 256, 0, stream>>>(
            aggrP, wt1p + (size_t)l * 512 * 224,
            b1 + (size_t)l * 400, nullptr, h1p, nullptr, N_NODES, 224, 400, 416, 7);
        hipMemsetAsync(stats, 0, 512 * 4, stream);
        gemm_mfma<2, 4, 1, 0, 0, 1><<<g2d, 256, 0, stream>>>(
            h1p, wt2p + (size_t)l * 256 * 416,
            b2 + (size_t)l * 200, g2, nullptr, stats, N_NODES, 416, 200, 200, 13);
    }

    pool_bn_kernel<<<(NGRAPH * 50 + 255) / 256, 256, 0, stream>>>(
        g2, stats, gamma + (size_t)(NLAYERS - 1) * D, beta + (size_t)(NLAYERS - 1) * D,
        gstart, hg);

    dim3 gp((NGRAPH + BM - 1) / BM, (D + BNT - 1) / BNT);
    gemm_kernel<<<gp, 256, 0, stream>>>(hg, feat_w, feat_b, outf, NGRAPH, D, D, 0);
    gemm_kernel<<<gp, 256, 0, stream>>>(outf, out_w1, out_b1, tbuf, NGRAPH, D, D, 1);
    dim3 go((NGRAPH + BM - 1) / BM, (100 + BNT - 1) / BNT);
    gemm_kernel<<<go, 256, 0, stream>>>(tbuf, out_w2, out_b2, outf + (size_t)NGRAPH * D,
                                        NGRAPH, D, 100, 0);
    hipMemcpyAsync(outf + (size_t)NGRAPH * D + (size_t)NGRAPH * 100,
                   outf + (size_t)NGRAPH * D,
                   (size_t)NGRAPH * 100 * 4, hipMemcpyDeviceToDevice, stream);
}

// Round 10
// 2139.119 us; speedup vs baseline: 1.1241x; 1.1241x over previous
//
#include <hip/hip_runtime.h>

#define N_NODES 50000
#define N_EDGES 200000
#define D 200
#define NLAYERS 10
#define NGRAPH 2500
#define EPS 1e-5f

typedef unsigned short u16;
typedef unsigned int u32;
typedef __attribute__((ext_vector_type(8))) __bf16 bf16x8;
typedef __attribute__((ext_vector_type(4))) float f32x4;

// fp32 -> bf16 RNE
__device__ __forceinline__ u16 f2bf_rne(float x) {
    union { float f; unsigned u; } c; c.f = x;
    unsigned r = c.u + 0x7FFF + ((c.u >> 16) & 1);
    return (u16)(r >> 16);
}
// packed: low u16 = hi bf16, high u16 = lo bf16
__device__ __forceinline__ u32 split_pack(float x) {
    u16 h = f2bf_rne(x);
    union { unsigned u; float f; } c; c.u = ((unsigned)h) << 16;
    u16 l = f2bf_rne(x - c.f);
    return (u32)h | ((u32)l << 16);
}

// ---------------- CSR build -------------------------------------------------

__global__ void count_kernel(const int* __restrict__ dst, int* __restrict__ counts) {
    int e = blockIdx.x * 256 + threadIdx.x;
    if (e < N_EDGES) atomicAdd(&counts[dst[e]], 1);
}

__global__ void scan1_kernel(const int* __restrict__ counts, int* __restrict__ psum) {
    __shared__ int s[256];
    int idx = blockIdx.x * 256 + threadIdx.x;
    s[threadIdx.x] = (idx < N_NODES) ? counts[idx] : 0;
    __syncthreads();
    for (int off = 128; off > 0; off >>= 1) {
        if (threadIdx.x < off) s[threadIdx.x] += s[threadIdx.x + off];
        __syncthreads();
    }
    if (threadIdx.x == 0) psum[blockIdx.x] = s[0];
}

__global__ void scan2_kernel(const int* __restrict__ psum, int* __restrict__ poff, int nchunk) {
    __shared__ int s[256];
    int t = threadIdx.x;
    int v = (t < nchunk) ? psum[t] : 0;
    s[t] = v;
    __syncthreads();
    for (int off = 1; off < 256; off <<= 1) {
        int xv = (t >= off) ? s[t - off] : 0;
        __syncthreads();
        s[t] += xv;
        __syncthreads();
    }
    if (t < nchunk) poff[t] = s[t] - v;
}

__global__ void scan3_kernel(const int* __restrict__ counts, const int* __restrict__ poff,
                             int* __restrict__ row_start, int* __restrict__ cursor) {
    __shared__ int s[256];
    int t = threadIdx.x;
    int idx = blockIdx.x * 256 + t;
    int v = (idx < N_NODES) ? counts[idx] : 0;
    s[t] = v;
    __syncthreads();
    for (int off = 1; off < 256; off <<= 1) {
        int xv = (t >= off) ? s[t - off] : 0;
        __syncthreads();
        s[t] += xv;
        __syncthreads();
    }
    if (idx < N_NODES) {
        int rs = poff[blockIdx.x] + s[t] - v;
        row_start[idx] = rs;
        cursor[idx] = rs;
    }
    if (blockIdx.x == 0 && t == 0) row_start[N_NODES] = N_EDGES;
}

__global__ void scatter_kernel(const int* __restrict__ dst, int* __restrict__ cursor,
                               int* __restrict__ edge_list) {
    int e = blockIdx.x * 256 + threadIdx.x;
    if (e < N_EDGES) {
        int p = atomicAdd(&cursor[dst[e]], 1);
        edge_list[p] = e;
    }
}

__global__ void bounds_kernel(const int* __restrict__ batch, int* __restrict__ gstart) {
    int g = blockIdx.x * 256 + threadIdx.x;
    if (g > NGRAPH) return;
    if (g == NGRAPH) { gstart[NGRAPH] = N_NODES; return; }
    int lo = 0, hi = N_NODES;
    while (lo < hi) { int mid = (lo + hi) >> 1; if (batch[mid] < g) lo = mid + 1; else hi = mid; }
    gstart[g] = lo;
}

// ---------------- weight prep: transpose + pad + packed hi/lo bf16 -----------

__global__ void prep_w1_kernel(const float* __restrict__ w, u32* __restrict__ wp) {
    int idx = blockIdx.x * 256 + threadIdx.x;
    if (idx >= NLAYERS * 512 * 224) return;
    int k = idx % 224;
    int n = (idx / 224) % 512;
    int l = idx / (224 * 512);
    float v = (k < 200 && n < 400) ? w[((size_t)l * 200 + k) * 400 + n] : 0.f;
    wp[idx] = split_pack(v);
}

__global__ void prep_w2_kernel(const float* __restrict__ w, u32* __restrict__ wp) {
    int idx = blockIdx.x * 256 + threadIdx.x;
    if (idx >= NLAYERS * 256 * 416) return;
    int k = idx % 416;
    int n = (idx / 416) % 256;
    int l = idx / (416 * 256);
    float v = (k < 400 && n < 200) ? w[((size_t)l * 400 + k) * 200 + n] : 0.f;
    wp[idx] = split_pack(v);
}

// ---------------- node feature init ------------------------------------------

__global__ void embed_kernel(const int* __restrict__ x, const float* __restrict__ emb1,
                             const float* __restrict__ emb2, float* __restrict__ h) {
    int idx = blockIdx.x * 256 + threadIdx.x;
    if (idx >= N_NODES * 50) return;
    int node = idx / 50;
    int c = (idx % 50) * 4;
    int a = x[node * 2], b = x[node * 2 + 1];
    float4 v1 = *(const float4*)(emb1 + (size_t)a * D + c);
    float4 v2 = *(const float4*)(emb2 + (size_t)b * D + c);
    float4 o;
    o.x = v1.x + v2.x; o.y = v1.y + v2.y; o.z = v1.z + v2.z; o.w = v1.w + v2.w;
    *(float4*)(h + (size_t)node * D + c) = o;
}

// ---------------- message + aggregate: one WAVE per node ----------------------
// Edge indices loaded once per wave (wave-uniform) instead of once per chunk-
// thread (56x redundancy eliminated). +fused BN-norm+ReLU of previous layer.

template <int HAS_BN>
__global__ void aggregate_kernel(const float* __restrict__ hin,
                                 const float* __restrict__ stats,
                                 const float* __restrict__ gamma, const float* __restrict__ beta,
                                 const float* __restrict__ e1, const float* __restrict__ e2,
                                 const int* __restrict__ row_start, const int* __restrict__ edge_list,
                                 const int* __restrict__ src, const int* __restrict__ edge_attr,
                                 u32* __restrict__ Ap) {
    __shared__ float t1[5 * D];
    __shared__ float t2[3 * D];
    for (int i = threadIdx.x; i < 5 * D; i += 256) t1[i] = e1[i];
    for (int i = threadIdx.x; i < 3 * D; i += 256) t2[i] = e2[i];
    __syncthreads();
    int node = blockIdx.x * 4 + (threadIdx.x >> 6);
    int lane = threadIdx.x & 63;
    if (node >= N_NODES || lane >= 56) return;
    int c = lane * 4;
    size_t ob = (size_t)node * 224 + c;
    if (c >= 200) {  // K padding cols 200..223
        *(uint4*)(Ap + ob) = make_uint4(0u, 0u, 0u, 0u);
        return;
    }
    float a[4], b[4];
    if (HAS_BN) {
        const float invN = 1.0f / (float)N_NODES;
#pragma unroll
        for (int j = 0; j < 4; ++j) {
            float s = stats[c + j], q = stats[256 + c + j];
            float m = s * invN;
            float var = q * invN - m * m;
            float sc = gamma[c + j] * rsqrtf(var + EPS);
            a[j] = sc; b[j] = beta[c + j] - m * sc;
        }
    }
    float4 acc = *(const float4*)(hin + (size_t)node * D + c);
    if (HAS_BN) {
        acc.x = fmaxf(acc.x * a[0] + b[0], 0.f);
        acc.y = fmaxf(acc.y * a[1] + b[1], 0.f);
        acc.z = fmaxf(acc.z * a[2] + b[2], 0.f);
        acc.w = fmaxf(acc.w * a[3] + b[3], 0.f);
    }
    acc.x += t1[4 * D + c + 0] + t2[c + 0];
    acc.y += t1[4 * D + c + 1] + t2[c + 1];
    acc.z += t1[4 * D + c + 2] + t2[c + 2];
    acc.w += t1[4 * D + c + 3] + t2[c + 3];
    int jb = row_start[node], je = row_start[node + 1];
    for (int j = jb; j < je; ++j) {
        int e = edge_list[j];              // wave-uniform -> s_load
        int s = src[e];
        int2 eav = *(const int2*)(edge_attr + 2 * e);
        float4 hv = *(const float4*)(hin + (size_t)s * D + c);
        if (HAS_BN) {
            hv.x = fmaxf(hv.x * a[0] + b[0], 0.f);
            hv.y = fmaxf(hv.y * a[1] + b[1], 0.f);
            hv.z = fmaxf(hv.z * a[2] + b[2], 0.f);
            hv.w = fmaxf(hv.w * a[3] + b[3], 0.f);
        }
        const float* p1 = t1 + eav.x * D + c;
        const float* p2 = t2 + eav.y * D + c;
        acc.x += hv.x + p1[0] + p2[0];
        acc.y += hv.y + p1[1] + p2[1];
        acc.z += hv.z + p1[2] + p2[2];
        acc.w += hv.w + p1[3] + p2[3];
    }
    uint4 pv;
    pv.x = split_pack(acc.x); pv.y = split_pack(acc.y);
    pv.z = split_pack(acc.z); pv.w = split_pack(acc.w);
    *(uint4*)(Ap + ob) = pv;
}

// ---------------- bf16x2 MFMA GEMM (round-4 verified structure + XCD swizzle) -
// Block tile (FM*32) x (FN*32), 4 waves 2x2, K-step 32, 16x16x32 MFMA.
// Staging-side unpack: packed u32 global -> separate hi/lo u16 LDS arrays.
// LDS swizzle: elem offset(row, g) = row*32 + ((g ^ ((row>>1)&3))*8) (0 conflicts, measured r2-r7).
// XCD-bijective block swizzle (m204): blocks on one XCD cover a contiguous
// tile range -> A row-band L2 reuse (FETCH halved, measured r8).

template <int FM, int FN, int GXL, int RELU, int WRITE_PACKED, int STATS>
__global__ __launch_bounds__(256) void gemm_mfma(
    const u32* __restrict__ Ap, const u32* __restrict__ Bp,
    const float* __restrict__ bias,
    float* __restrict__ Cf, u32* __restrict__ Cp,
    float* __restrict__ stats,
    int M, int Kpad, int Nc, int NcPad, int KT)
{
    constexpr int BMT = FM * 32;           // block M tile (128)
    constexpr int BNTL = FN * 32;          // block N tile (128)
    constexpr int RA = BMT / 64;           // A row-halves per thread (2)
    constexpr int RB = BNTL / 64;          // B row-halves per thread (2)

    __shared__ alignas(16) u16 sAh[BMT * 32];
    __shared__ alignas(16) u16 sAl[BMT * 32];
    __shared__ alignas(16) u16 sBh[BNTL * 32];
    __shared__ alignas(16) u16 sBl[BNTL * 32];

    const int tid = threadIdx.x;
    const int lane = tid & 63;
    const int wid = tid >> 6;
    const int wm = wid >> 1, wn = wid & 1;
    const int lr = lane & 15, lg = lane >> 4;

    // XCD-bijective swizzle: hw XCD = id%8; give each XCD a contiguous tile chunk
    const int nwg = (int)(gridDim.x * gridDim.y);
    const int id = (int)(blockIdx.y * gridDim.x + blockIdx.x);
    const int q = nwg >> 3, rm = nwg & 7;
    const int xcd = id & 7, sub = id >> 3;
    const int wgid = (xcd < rm ? xcd * (q + 1) : rm * (q + 1) + (xcd - rm) * q) + sub;
    const int bm0 = (wgid >> GXL) * BMT;
    const int bn0 = (wgid & ((1 << GXL) - 1)) * BNTL;

    // staging: thread -> row r0 (+64 per extra half), k-granule gd (8 elems)
    const int r0 = tid >> 2;
    const int gd = tid & 3;
    const int slot = gd ^ ((r0 >> 1) & 3);
    const int lO0 = r0 * 32 + slot * 8;       // u16-elem offset within a 64-row half
    const size_t gA = (size_t)(bm0 + r0) * Kpad + gd * 8;
    const size_t gB = (size_t)(bn0 + r0) * Kpad + gd * 8;

    f32x4 acc[FM][FN];
#pragma unroll
    for (int i = 0; i < FM; ++i)
#pragma unroll
        for (int j = 0; j < FN; ++j) acc[i][j] = (f32x4){0.f, 0.f, 0.f, 0.f};

    int aoff[FM], boff[FN];
#pragma unroll
    for (int f = 0; f < FM; ++f) {
        int arow = wm * FM * 16 + f * 16 + lr;
        aoff[f] = arow * 32 + ((lg ^ ((arow >> 1) & 3)) * 8);
    }
#pragma unroll
    for (int f = 0; f < FN; ++f) {
        int brow = wn * FN * 16 + f * 16 + lr;
        boff[f] = brow * 32 + ((lg ^ ((brow >> 1) & 3)) * 8);
    }

    uint4 pa[RA][2], pb[RB][2];
#define LOADT(K0)                                                                        \
    {                                                                                    \
        _Pragma("unroll")                                                                \
        for (int rr = 0; rr < RA; ++rr) {                                                \
            pa[rr][0] = *(const uint4*)(Ap + gA + (size_t)rr * 64 * Kpad + (K0));        \
            pa[rr][1] = *(const uint4*)(Ap + gA + (size_t)rr * 64 * Kpad + (K0) + 4);    \
        }                                                                                \
        _Pragma("unroll")                                                                \
        for (int rr = 0; rr < RB; ++rr) {                                                \
            pb[rr][0] = *(const uint4*)(Bp + gB + (size_t)rr * 64 * Kpad + (K0));        \
            pb[rr][1] = *(const uint4*)(Bp + gB + (size_t)rr * 64 * Kpad + (K0) + 4);    \
        }                                                                                \
    }

#define UNPACK_STORE(a, b, ph, pl)                                        \
    {                                                                     \
        uint4 hh, ll;                                                     \
        hh.x = __byte_perm((a).x, (a).y, 0x5410);                         \
        hh.y = __byte_perm((a).z, (a).w, 0x5410);                         \
        hh.z = __byte_perm((b).x, (b).y, 0x5410);                         \
        hh.w = __byte_perm((b).z, (b).w, 0x5410);                         \
        ll.x = __byte_perm((a).x, (a).y, 0x7632);                         \
        ll.y = __byte_perm((a).z, (a).w, 0x7632);                         \
        ll.z = __byte_perm((b).x, (b).y, 0x7632);                         \
        ll.w = __byte_perm((b).z, (b).w, 0x7632);                         \
        *(uint4*)(ph) = hh;                                               \
        *(uint4*)(pl) = ll;                                               \
    }

    LOADT(0)
    for (int kt = 0; kt < KT; ++kt) {
        if (kt > 0) __syncthreads();
#pragma unroll
        for (int rr = 0; rr < RA; ++rr)
            UNPACK_STORE(pa[rr][0], pa[rr][1], sAh + rr * 2048 + lO0, sAl + rr * 2048 + lO0)
#pragma unroll
        for (int rr = 0; rr < RB; ++rr)
            UNPACK_STORE(pb[rr][0], pb[rr][1], sBh + rr * 2048 + lO0, sBl + rr * 2048 + lO0)
        __syncthreads();
        if (kt + 1 < KT) { LOADT((size_t)(kt + 1) * 32) }

        bf16x8 fbh[FN], fbl[FN];
#pragma unroll
        for (int fn = 0; fn < FN; ++fn) {
            fbh[fn] = *(const bf16x8*)(sBh + boff[fn]);
            fbl[fn] = *(const bf16x8*)(sBl + boff[fn]);
        }
#pragma unroll
        for (int fm = 0; fm < FM; ++fm) {
            bf16x8 fah = *(const bf16x8*)(sAh + aoff[fm]);
            bf16x8 fal = *(const bf16x8*)(sAl + aoff[fm]);
#pragma unroll
            for (int fn = 0; fn < FN; ++fn) {
                acc[fm][fn] = __builtin_amdgcn_mfma_f32_16x16x32_bf16(fah, fbh[fn], acc[fm][fn], 0, 0, 0);
                acc[fm][fn] = __builtin_amdgcn_mfma_f32_16x16x32_bf16(fah, fbl[fn], acc[fm][fn], 0, 0, 0);
                acc[fm][fn] = __builtin_amdgcn_mfma_f32_16x16x32_bf16(fal, fbh[fn], acc[fm][fn], 0, 0, 0);
            }
        }
    }
#undef LOADT
#undef UNPACK_STORE

    // epilogue: frag D row = lg*4+r, col = lr
#pragma unroll
    for (int fn = 0; fn < FN; ++fn) {
        int col = bn0 + wn * FN * 16 + fn * 16 + lr;
        float bv = (col < Nc) ? bias[col] : 0.f;
        if (WRITE_PACKED) {
            if (col < NcPad) {
#pragma unroll
                for (int fm = 0; fm < FM; ++fm) {
#pragma unroll
                    for (int r = 0; r < 4; ++r) {
                        int row = bm0 + wm * FM * 16 + fm * 16 + lg * 4 + r;
                        if (row < M) {
                            float v = acc[fm][fn][r] + bv;
                            if (RELU) v = fmaxf(v, 0.f);
                            if (col >= Nc) v = 0.f;   // h1 K-padding cols must be 0
                            Cp[(size_t)row * NcPad + col] = split_pack(v);
                        }
                    }
                }
            }
        } else {
            float s = 0.f, q2 = 0.f;
#pragma unroll
            for (int fm = 0; fm < FM; ++fm) {
#pragma unroll
                for (int r = 0; r < 4; ++r) {
                    int row = bm0 + wm * FM * 16 + fm * 16 + lg * 4 + r;
                    if (row < M && col < Nc) {
                        float v = acc[fm][fn][r] + bv;
                        if (RELU) v = fmaxf(v, 0.f);
                        Cf[(size_t)row * Nc + col] = v;
                        if (STATS) { s += v; q2 += v * v; }
                    }
                }
            }
            if (STATS) {
                s += __shfl_xor(s, 16); s += __shfl_xor(s, 32);
                q2 += __shfl_xor(q2, 16); q2 += __shfl_xor(q2, 32);
                if (lg == 0 && col < Nc) {
                    atomicAdd(&stats[col], s);
                    atomicAdd(&stats[256 + col], q2);
                }
            }
        }
    }
}

// ---------------- fp32 tiled GEMM (tail, small M) ----------------------------

#define BM 128
#define BNT 64
#define BK 8

__global__ __launch_bounds__(256) void gemm_kernel(const float* __restrict__ A,
                                                   const float* __restrict__ W,
                                                   const float* __restrict__ bias,
                                                   float* __restrict__ C,
                                                   int M, int K, int Nc, int relu) {
    __shared__ float As[BK][BM];
    __shared__ float Bs[BK][BNT];
    int tid = threadIdx.x;
    int bm = blockIdx.x * BM;
    int bn = blockIdx.y * BNT;
    int tx = tid & 15, ty = tid >> 4;

    float acc[8][4];
#pragma unroll
    for (int i = 0; i < 8; ++i)
#pragma unroll
        for (int j = 0; j < 4; ++j) acc[i][j] = 0.f;

    int ar = tid >> 1;
    int ak = (tid & 1) << 2;
    int bk = tid >> 5;
    int bcol = (tid & 31) << 1;

    for (int k0 = 0; k0 < K; k0 += BK) {
        float4 av = {0.f, 0.f, 0.f, 0.f};
        int row = bm + ar;
        if (row < M) av = *(const float4*)(A + (size_t)row * K + k0 + ak);
        As[ak + 0][ar] = av.x; As[ak + 1][ar] = av.y;
        As[ak + 2][ar] = av.z; As[ak + 3][ar] = av.w;
        float2 bv = {0.f, 0.f};
        int col = bn + bcol;
        if (col < Nc) bv = *(const float2*)(W + (size_t)(k0 + bk) * Nc + col);
        Bs[bk][bcol] = bv.x; Bs[bk][bcol + 1] = bv.y;
        __syncthreads();
#pragma unroll
        for (int kk = 0; kk < BK; ++kk) {
            float a[8], b[4];
            *(float4*)(a)     = *(const float4*)(&As[kk][ty * 8]);
            *(float4*)(a + 4) = *(const float4*)(&As[kk][ty * 8 + 4]);
            *(float4*)(b)     = *(const float4*)(&Bs[kk][tx * 4]);
#pragma unroll
            for (int i = 0; i < 8; ++i)
#pragma unroll
                for (int j = 0; j < 4; ++j) acc[i][j] = fmaf(a[i], b[j], acc[i][j]);
        }
        __syncthreads();
    }

#pragma unroll
    for (int i = 0; i < 8; ++i) {
        int row = bm + ty * 8 + i;
        if (row < M) {
            int col = bn + tx * 4;
            if (col < Nc) {
                float4 bb = *(const float4*)(bias + col);
                float4 v;
                v.x = acc[i][0] + bb.x; v.y = acc[i][1] + bb.y;
                v.z = acc[i][2] + bb.z; v.w = acc[i][3] + bb.w;
                if (relu) {
                    v.x = fmaxf(v.x, 0.f); v.y = fmaxf(v.y, 0.f);
                    v.z = fmaxf(v.z, 0.f); v.w = fmaxf(v.w, 0.f);
                }
                *(float4*)(C + (size_t)row * Nc + col) = v;
            }
        }
    }
}

// ---------------- global mean pool (+fused BN of last layer, no relu) --------

__global__ void pool_bn_kernel(const float* __restrict__ g2, const float* __restrict__ stats,
                               const float* __restrict__ gamma, const float* __restrict__ beta,
                               const int* __restrict__ gstart, float* __restrict__ hg) {
    int idx = blockIdx.x * 256 + threadIdx.x;
    if (idx >= NGRAPH * 50) return;
    int g = idx / 50;
    int c = (idx % 50) * 4;
    float a[4], b[4];
    const float invN = 1.0f / (float)N_NODES;
#pragma unroll
    for (int j = 0; j < 4; ++j) {
        float s = stats[c + j], q = stats[256 + c + j];
        float m = s * invN;
        float var = q * invN - m * m;
        float sc = gamma[c + j] * rsqrtf(var + EPS);
        a[j] = sc; b[j] = beta[c + j] - m * sc;
    }
    int s0 = gstart[g], e0 = gstart[g + 1];
    float4 acc = {0.f, 0.f, 0.f, 0.f};
    for (int r = s0; r < e0; ++r) {
        float4 v = *(const float4*)(g2 + (size_t)r * D + c);
        acc.x += v.x; acc.y += v.y; acc.z += v.z; acc.w += v.w;
    }
    float inv = 1.0f / fmaxf((float)(e0 - s0), 1.0f);
    acc.x = acc.x * inv * a[0] + b[0];
    acc.y = acc.y * inv * a[1] + b[1];
    acc.z = acc.z * inv * a[2] + b[2];
    acc.w = acc.w * inv * a[3] + b[3];
    *(float4*)(hg + (size_t)g * D + c) = acc;
}

// ---------------- launch -------------------------------------------------------

extern "C" void kernel_launch(void* const* d_in, const int* in_sizes, int n_in,
                              void* d_out, int out_size, void* d_ws, size_t ws_size,
                              hipStream_t stream) {
    const int*   x       = (const int*)d_in[0];
    const int*   ei      = (const int*)d_in[1];
    const int*   ea      = (const int*)d_in[2];
    const int*   batch   = (const int*)d_in[3];
    const float* x_emb1  = (const float*)d_in[4];
    const float* x_emb2  = (const float*)d_in[5];
    const float* e1w     = (const float*)d_in[6];
    const float* e2w     = (const float*)d_in[7];
    const float* w1      = (const float*)d_in[8];
    const float* b1      = (const float*)d_in[9];
    const float* w2      = (const float*)d_in[10];
    const float* b2      = (const float*)d_in[11];
    const float* gamma   = (const float*)d_in[12];
    const float* beta    = (const float*)d_in[13];
    const float* feat_w  = (const float*)d_in[14];
    const float* feat_b  = (const float*)d_in[15];
    const float* out_w1  = (const float*)d_in[16];
    const float* out_b1  = (const float*)d_in[17];
    const float* out_w2  = (const float*)d_in[18];
    const float* out_b2  = (const float*)d_in[19];
    const int* src = ei;
    const int* dst = ei + N_EDGES;

    char* p = (char*)d_ws;
    auto alloc = [&](size_t bytes) -> void* {
        void* r = (void*)p;
        p += (bytes + 255) & ~(size_t)255;
        return r;
    };
    const int MPAD = 50048;                         // 391*128
    float* h      = (float*)alloc((size_t)N_NODES * D * 4);          // 40 MB
    float* g2     = h;
    u32*   aggrP  = (u32*)alloc((size_t)MPAD * 224 * 4);             // 44.8 MB
    u32*   h1p    = (u32*)alloc((size_t)MPAD * 416 * 4);             // 83.3 MB
    u32*   wt1p   = (u32*)alloc((size_t)NLAYERS * 512 * 224 * 4);    // 4.6 MB
    u32*   wt2p   = (u32*)alloc((size_t)NLAYERS * 256 * 416 * 4);    // 4.3 MB
    int*   counts    = (int*)alloc(N_NODES * 4);
    int*   row_start = (int*)alloc((N_NODES + 1) * 4);
    int*   cursor    = (int*)alloc(N_NODES * 4);
    int*   edge_list = (int*)alloc(N_EDGES * 4);
    int*   psum      = (int*)alloc(256 * 4);
    int*   poff      = (int*)alloc(256 * 4);
    int*   gstart    = (int*)alloc((NGRAPH + 1) * 4);
    float* stats     = (float*)alloc(512 * 4);       // [sum 256][sumsq 256]
    float* hg        = (float*)alloc((size_t)NGRAPH * D * 4);
    float* tbuf      = (float*)alloc((size_t)NGRAPH * D * 4);
    float* outf      = (float*)d_out;

    const int NCHUNK = (N_NODES + 255) / 256;

    // weight prep (once per launch)
    prep_w1_kernel<<<(NLAYERS * 512 * 224 + 255) / 256, 256, 0, stream>>>(w1, wt1p);
    prep_w2_kernel<<<(NLAYERS * 256 * 416 + 255) / 256, 256, 0, stream>>>(w2, wt2p);

    // CSR build + graph bounds
    hipMemsetAsync(counts, 0, N_NODES * 4, stream);
    count_kernel<<<(N_EDGES + 255) / 256, 256, 0, stream>>>(dst, counts);
    scan1_kernel<<<NCHUNK, 256, 0, stream>>>(counts, psum);
    scan2_kernel<<<1, 256, 0, stream>>>(psum, poff, NCHUNK);
    scan3_kernel<<<NCHUNK, 256, 0, stream>>>(counts, poff, row_start, cursor);
    scatter_kernel<<<(N_EDGES + 255) / 256, 256, 0, stream>>>(dst, cursor, edge_list);
    bounds_kernel<<<(NGRAPH + 1 + 255) / 256, 256, 0, stream>>>(batch, gstart);

    embed_kernel<<<(N_NODES * 50 + 255) / 256, 256, 0, stream>>>(x, x_emb1, x_emb2, h);

    dim3 g1(4, 391);    // GEMM1: 128x128 tiles, N pad 512  (GXL=2)
    dim3 g2d(2, 391);   // GEMM2: 128x128 tiles, N pad 256  (GXL=1)
    for (int l = 0; l < NLAYERS; ++l) {
        if (l == 0)
            aggregate_kernel<0><<<12500, 256, 0, stream>>>(
                h, nullptr, nullptr, nullptr,
                e1w, e2w, row_start, edge_list, src, ea, aggrP);
        else
            aggregate_kernel<1><<<12500, 256, 0, stream>>>(
                g2, stats, gamma + (size_t)(l - 1) * D, beta + (size_t)(l - 1) * D,
                e1w + (size_t)l * 5 * D, e2w + (size_t)l * 3 * D,
                row_start, edge_list, src, ea, aggrP);
        gemm_mfma<4, 4, 2, 1, 1, 0><<<g1, 256, 0, stream>>>(
            aggrP, wt1p + (size_t)l * 512 * 224,
            b1 + (size_t)l * 400, nullptr, h1p, nullptr, N_NODES, 224, 400, 416, 7);
        hipMemsetAsync(stats, 0, 512 * 4, stream);
        gemm_mfma<4, 4, 1, 0, 0, 1><<<g2d, 256, 0, stream>>>(
            h1p, wt2p + (size_t)l * 256 * 416,
            b2 + (size_t)l * 200, g2, nullptr, stats, N_NODES, 416, 200, 200, 13);
    }

    pool_bn_kernel<<<(NGRAPH * 50 + 255) / 256, 256, 0, stream>>>(
        g2, stats, gamma + (size_t)(NLAYERS - 1) * D, beta + (size_t)(NLAYERS - 1) * D,
        gstart, hg);

    dim3 gp((NGRAPH + BM - 1) / BM, (D + BNT - 1) / BNT);
    gemm_kernel<<<gp, 256, 0, stream>>>(hg, feat_w, feat_b, outf, NGRAPH, D, D, 0);
    gemm_kernel<<<gp, 256, 0, stream>>>(outf, out_w1, out_b1, tbuf, NGRAPH, D, D, 1);
    dim3 go((NGRAPH + BM - 1) / BM, (100 + BNT - 1) / BNT);
    gemm_kernel<<<go, 256, 0, stream>>>(tbuf, out_w2, out_b2, outf + (size_t)NGRAPH * D,
                                        NGRAPH, D, 100, 0);
    hipMemcpyAsync(outf + (size_t)NGRAPH * D + (size_t)NGRAPH * 100,
                   outf + (size_t)NGRAPH * D,
                   (size_t)NGRAPH * 100 * 4, hipMemcpyDeviceToDevice, stream);
}